// Round 1
// baseline (532.274 us; speedup 1.0000x reference)
//
#include <hip/hip_runtime.h>
#include <math.h>

#define B 128
#define D 128
#define NMEM 100000
#define KTOT 8194
#define NEGK 8192
#define CHUNKS 8
#define CS 1025  // ceil(8194/8)

__device__ __forceinline__ float wave_allreduce(float v) {
    #pragma unroll
    for (int off = 1; off < 64; off <<= 1) v += __shfl_xor(v, off, 64);
    return v;
}

// One block per (chunk, b). 4 waves; each wave handles one k at a time.
// Streams all per-row reduction statistics (no logit materialization).
__global__ __launch_bounds__(256) void gather_logits(
        const float* __restrict__ emb0, const float* __restrict__ emb1,
        const float* __restrict__ mem0, const float* __restrict__ mem1,
        const int* __restrict__ pos_idx, const int* __restrict__ neg_idx,
        float* __restrict__ partials) {
    const int c = blockIdx.x;
    const int b = blockIdx.y;
    const int tid = threadIdx.x;
    const int lane = tid & 63;
    const int w = tid >> 6;
    const float INV_TAU = 1.0f / 0.07f;
    const float INV3 = 1.0f / 3.0f;

    const float2 e0 = *(const float2*)(emb0 + b * D + 2 * lane);
    const float2 e1 = *(const float2*)(emb1 + b * D + 2 * lane);

    float s1ij = 0.f, s1ji = 0.f, s1i0 = 0.f, s1i1 = 0.f;
    float s3ij = 0.f, s3ji = 0.f, s3i0 = 0.f, s3i1 = 0.f;
    float wa = 0.f, wb = 0.f, wc = 0.f, wd = 0.f;
    float sp0 = 0.f, sp1 = 0.f, sp2 = 0.f, sp3 = 0.f, sp4 = 0.f, sp5 = 0.f;

    const int k0 = c * CS;
    const int kend = (k0 + CS < KTOT) ? k0 + CS : KTOT;
    for (int k = k0 + w; k < kend; k += 4) {
        const int r = (k < 2) ? pos_idx[b * 2 + k] : neg_idx[b * NEGK + (k - 2)];
        const float2 m0 = *(const float2*)(mem0 + r * D + 2 * lane);
        const float2 m1 = *(const float2*)(mem1 + r * D + 2 * lane);
        float pij = m0.x * e1.x + m0.y * e1.y;  // cij    = mem0 . emb1
        float pii = m0.x * e0.x + m0.y * e0.y;  // intra0 = mem0 . emb0
        float pji = m1.x * e0.x + m1.y * e0.y;  // cji    = mem1 . emb0
        float pjj = m1.x * e1.x + m1.y * e1.y;  // intra1 = mem1 . emb1
        pij = wave_allreduce(pij);
        pii = wave_allreduce(pii);
        pji = wave_allreduce(pji);
        pjj = wave_allreduce(pjj);
        const float cij = pij * INV_TAU, ci0 = pii * INV_TAU;
        const float cji = pji * INV_TAU, ci1 = pjj * INV_TAU;
        const float e3ij = __expf(cij * INV3), e3ji = __expf(cji * INV3);
        s1ij += __expf(cij);
        s1ji += __expf(cji);
        s3ij += e3ij;
        s3ji += e3ji;
        wa += e3ji * (cji - cij);
        wb += e3ij * (cij - cji);
        if (k >= 1) {  // intra logits cover k in [1, KTOT)
            const float e3i0 = __expf(ci0 * INV3), e3i1 = __expf(ci1 * INV3);
            s1i0 += __expf(ci0);
            s1i1 += __expf(ci1);
            s3i0 += e3i0;
            s3i1 += e3i1;
            wc += e3i1 * (ci1 - ci0);
            wd += e3i0 * (ci0 - ci1);
        }
        if (k == 0) { sp0 = cij; sp2 = cji; }
        if (k == 1) { sp1 = cij; sp3 = cji; sp4 = ci0; sp5 = ci1; }
    }

    __shared__ float red[4][12];
    __shared__ float sps[6];
    if (lane == 0) {
        float v[12] = {s1ij, s1ji, s1i0, s1i1, s3ij, s3ji, s3i0, s3i1, wa, wb, wc, wd};
        #pragma unroll
        for (int j = 0; j < 12; ++j) red[w][j] = v[j];
        if (w == 0) { sps[0] = sp0; sps[2] = sp2; }
        if (w == 1) { sps[1] = sp1; sps[3] = sp3; sps[4] = sp4; sps[5] = sp5; }
    }
    __syncthreads();
    float* outp = partials + (b * CHUNKS + c) * 20;
    if (tid < 12) outp[tid] = red[0][tid] + red[1][tid] + red[2][tid] + red[3][tid];
    else if (tid < 18) outp[tid] = sps[tid - 12];
}

// Single block, 128 threads (one per b): merge chunk partials -> 4 scalars.
__global__ void finalize(const float* __restrict__ partials, float* __restrict__ out) {
    const int b = threadIdx.x;
    float a[12];
    #pragma unroll
    for (int j = 0; j < 12; ++j) a[j] = 0.f;
    for (int c = 0; c < CHUNKS; ++c) {
        const float* p = partials + (b * CHUNKS + c) * 20;
        #pragma unroll
        for (int j = 0; j < 12; ++j) a[j] += p[j];
    }
    const float* e = partials + (b * CHUNKS) * 20 + 12;
    const float cij0 = e[0], cij1 = e[1], cji0 = e[2], cji1 = e[3], i01 = e[4], i11 = e[5];
    // a: 0 s1ij, 1 s1ji, 2 s1i0, 3 s1i1, 4 s3ij, 5 s3ji, 6 s3i0, 7 s3i1, 8 wa, 9 wb, 10 wc, 11 wd
    const float icl_b = -((cij0 + cij1) * 0.5f - __logf(a[0]))
                        - ((cji0 + cji1) * 0.5f - __logf(a[1]));
    const float vcl_b = -(i01 - __logf(a[2])) - (i11 - __logf(a[3]));
    // kld(X,Y)+kld(Y,X): lse terms cancel; = 3/B * (wa/s3_Y + wb/s3_X)
    const float sicl_b = 3.0f * (a[8] / a[5] + a[9] / a[4]);
    const float svcl_b = 3.0f * (a[10] / a[7] + a[11] / a[6]);
    __shared__ float r[4][128];
    r[0][b] = vcl_b; r[1][b] = svcl_b; r[2][b] = icl_b; r[3][b] = sicl_b;
    __syncthreads();
    for (int s = 64; s > 0; s >>= 1) {
        if (b < s) {
            r[0][b] += r[0][b + s]; r[1][b] += r[1][b + s];
            r[2][b] += r[2][b + s]; r[3][b] += r[3][b + s];
        }
        __syncthreads();
    }
    if (b == 0) {
        out[0] = r[0][0] * (1.0f / 128.f);
        out[1] = r[1][0] * (1.0f / 128.f);
        out[2] = r[2][0] * (1.0f / 128.f);
        out[3] = r[3][0] * (1.0f / 128.f);
    }
}

__global__ void copy_mems(const float4* __restrict__ m0, const float4* __restrict__ m1,
                          float4* __restrict__ o0, float4* __restrict__ o1) {
    const int n4 = NMEM * D / 4;
    for (int i = blockIdx.x * blockDim.x + threadIdx.x; i < n4; i += gridDim.x * blockDim.x) {
        o0[i] = m0[i];
        o1[i] = m1[i];
    }
}

// One block per b; wave 0 -> net0, wave 1 -> net1. Last-write-wins on dup p0.
__global__ void update_rows(const float* __restrict__ emb0, const float* __restrict__ emb1,
                            const float* __restrict__ mem0, const float* __restrict__ mem1,
                            const int* __restrict__ pos_idx,
                            float* __restrict__ o0, float* __restrict__ o1) {
    const int b = blockIdx.x;
    const int tid = threadIdx.x;  // 128
    const int lane = tid & 63;
    const int net = tid >> 6;
    const int p0 = pos_idx[b * 2];
    bool skip = false;
    for (int b2 = b + 1; b2 < B; ++b2)
        if (pos_idx[b2 * 2] == p0) skip = true;  // numpy scatter: last write wins
    if (skip) return;  // uniform across block
    const float* mem = net ? mem1 : mem0;
    const float* emb = net ? emb1 : emb0;
    float* o = net ? o1 : o0;
    const float2 mv = *(const float2*)(mem + p0 * D + 2 * lane);
    const float2 ev = *(const float2*)(emb + b * D + 2 * lane);
    const float ux = 0.5f * mv.x + 0.5f * ev.x;
    const float uy = 0.5f * mv.y + 0.5f * ev.y;
    float ss = ux * ux + uy * uy;
    #pragma unroll
    for (int off = 1; off < 64; off <<= 1) ss += __shfl_xor(ss, off, 64);
    const float inv = 1.0f / sqrtf(ss);
    float2 wv; wv.x = ux * inv; wv.y = uy * inv;
    *(float2*)(o + p0 * D + 2 * lane) = wv;
}

extern "C" void kernel_launch(void* const* d_in, const int* in_sizes, int n_in,
                              void* d_out, int out_size, void* d_ws, size_t ws_size,
                              hipStream_t stream) {
    const float* emb0 = (const float*)d_in[0];
    const float* emb1 = (const float*)d_in[1];
    const float* mem0 = (const float*)d_in[2];
    const float* mem1 = (const float*)d_in[3];
    const int* pos_idx = (const int*)d_in[4];
    const int* neg_idx = (const int*)d_in[5];
    float* out = (float*)d_out;
    float* partials = (float*)d_ws;  // needs 128*8*20*4 = 80 KiB

    float* out_m0 = out + 4;
    float* out_m1 = out + 4 + NMEM * D;

    gather_logits<<<dim3(CHUNKS, B), 256, 0, stream>>>(emb0, emb1, mem0, mem1,
                                                       pos_idx, neg_idx, partials);
    finalize<<<1, 128, 0, stream>>>(partials, out);
    copy_mems<<<4096, 256, 0, stream>>>((const float4*)mem0, (const float4*)mem1,
                                        (float4*)out_m0, (float4*)out_m1);
    update_rows<<<B, 128, 0, stream>>>(emb0, emb1, mem0, mem1, pos_idx, out_m0, out_m1);
}

// Round 2
// 378.588 us; speedup vs baseline: 1.4059x; 1.4059x over previous
//
#include <hip/hip_runtime.h>
#include <math.h>

#define B 128
#define D 128
#define NMEM 100000
#define KTOT 8194
#define NEGK 8192
#define CHUNKS 16
#define CS 513  // ceil(8194/16)

__device__ __forceinline__ float half_allreduce(float v) {
    // reduce across a 32-lane half of the wave (xor offsets stay in-half)
    #pragma unroll
    for (int off = 1; off < 32; off <<= 1) v += __shfl_xor(v, off, 64);
    return v;
}

// One block per (chunk, b). 4 waves; each wave handles TWO k's per iteration:
// lanes 0-31 -> k, lanes 32-63 -> k+1. Each lane holds a float4 (1/32 of a row).
__global__ __launch_bounds__(256) void gather_logits(
        const float* __restrict__ emb0, const float* __restrict__ emb1,
        const float* __restrict__ mem0, const float* __restrict__ mem1,
        const int* __restrict__ pos_idx, const int* __restrict__ neg_idx,
        float* __restrict__ partials) {
    const int c = blockIdx.x;
    const int b = blockIdx.y;
    const int tid = threadIdx.x;
    const int lane = tid & 63;
    const int w = tid >> 6;
    const int half = lane >> 5;   // which of the 2 k's this lane serves
    const int lane5 = lane & 31;  // position within the row
    const float INV_TAU = 1.0f / 0.07f;
    const float INV3 = 1.0f / 3.0f;

    const float4 q0 = *(const float4*)(emb0 + b * D + lane5 * 4);
    const float4 q1 = *(const float4*)(emb1 + b * D + lane5 * 4);

    float s1ij = 0.f, s1ji = 0.f, s1i0 = 0.f, s1i1 = 0.f;
    float s3ij = 0.f, s3ji = 0.f, s3i0 = 0.f, s3i1 = 0.f;
    float wa = 0.f, wb = 0.f, wc = 0.f, wd = 0.f;
    float sp0 = 0.f, sp1 = 0.f, sp2 = 0.f, sp3 = 0.f, sp4 = 0.f, sp5 = 0.f;

    const int k0 = c * CS;
    const int kend = (k0 + CS < KTOT) ? k0 + CS : KTOT;
    for (int kb = k0 + w * 2; kb < kend; kb += 8) {
        const int k = kb + half;
        const bool act = (k < kend);
        const int kc = act ? k : (kend - 1);
        const int r = (kc < 2) ? pos_idx[b * 2 + kc] : neg_idx[b * NEGK + (kc - 2)];
        const float4 m0 = *(const float4*)(mem0 + r * D + lane5 * 4);
        const float4 m1 = *(const float4*)(mem1 + r * D + lane5 * 4);
        float pij = m0.x * q1.x + m0.y * q1.y + m0.z * q1.z + m0.w * q1.w;  // cij
        float pii = m0.x * q0.x + m0.y * q0.y + m0.z * q0.z + m0.w * q0.w;  // intra0
        float pji = m1.x * q0.x + m1.y * q0.y + m1.z * q0.z + m1.w * q0.w;  // cji
        float pjj = m1.x * q1.x + m1.y * q1.y + m1.z * q1.z + m1.w * q1.w;  // intra1
        pij = half_allreduce(pij);
        pii = half_allreduce(pii);
        pji = half_allreduce(pji);
        pjj = half_allreduce(pjj);
        if (act) {
            const float cij = pij * INV_TAU, ci0 = pii * INV_TAU;
            const float cji = pji * INV_TAU, ci1 = pjj * INV_TAU;
            const float e3ij = __expf(cij * INV3), e3ji = __expf(cji * INV3);
            s1ij += __expf(cij);
            s1ji += __expf(cji);
            s3ij += e3ij;
            s3ji += e3ji;
            wa += e3ji * (cji - cij);
            wb += e3ij * (cij - cji);
            if (k >= 1) {  // intra logits cover k in [1, KTOT)
                const float e3i0 = __expf(ci0 * INV3), e3i1 = __expf(ci1 * INV3);
                s1i0 += __expf(ci0);
                s1i1 += __expf(ci1);
                s3i0 += e3i0;
                s3i1 += e3i1;
                wc += e3i1 * (ci1 - ci0);
                wd += e3i0 * (ci0 - ci1);
            }
            if (kc == 0) { sp0 = cij; sp2 = cji; }
            if (kc == 1) { sp1 = cij; sp3 = cji; sp4 = ci0; sp5 = ci1; }
        }
    }

    // combine the two halves of each wave, then waves via LDS
    float v[12] = {s1ij, s1ji, s1i0, s1i1, s3ij, s3ji, s3i0, s3i1, wa, wb, wc, wd};
    #pragma unroll
    for (int j = 0; j < 12; ++j) v[j] += __shfl_xor(v[j], 32, 64);

    __shared__ float red[4][12];
    __shared__ float sps[6];
    if (lane == 0) {
        #pragma unroll
        for (int j = 0; j < 12; ++j) red[w][j] = v[j];
    }
    if (w == 0 && lane == 0) { sps[0] = sp0; sps[2] = sp2; }
    if (w == 0 && lane == 32) { sps[1] = sp1; sps[3] = sp3; sps[4] = sp4; sps[5] = sp5; }
    __syncthreads();
    float* outp = partials + (b * CHUNKS + c) * 20;
    if (tid < 12) outp[tid] = red[0][tid] + red[1][tid] + red[2][tid] + red[3][tid];
    else if (tid < 18) outp[tid] = sps[tid - 12];
}

// Single block, 128 threads (one per b): merge chunk partials -> 4 scalars.
__global__ void finalize(const float* __restrict__ partials, float* __restrict__ out) {
    const int b = threadIdx.x;
    float a[12];
    #pragma unroll
    for (int j = 0; j < 12; ++j) a[j] = 0.f;
    for (int c = 0; c < CHUNKS; ++c) {
        const float* p = partials + (b * CHUNKS + c) * 20;
        #pragma unroll
        for (int j = 0; j < 12; ++j) a[j] += p[j];
    }
    const float* e = partials + (b * CHUNKS) * 20 + 12;
    const float cij0 = e[0], cij1 = e[1], cji0 = e[2], cji1 = e[3], i01 = e[4], i11 = e[5];
    // a: 0 s1ij, 1 s1ji, 2 s1i0, 3 s1i1, 4 s3ij, 5 s3ji, 6 s3i0, 7 s3i1, 8 wa, 9 wb, 10 wc, 11 wd
    const float icl_b = -((cij0 + cij1) * 0.5f - __logf(a[0]))
                        - ((cji0 + cji1) * 0.5f - __logf(a[1]));
    const float vcl_b = -(i01 - __logf(a[2])) - (i11 - __logf(a[3]));
    // kld(X,Y)+kld(Y,X): lse terms cancel; = 3/B * (wa/s3_Y + wb/s3_X), B-mean later
    const float sicl_b = 3.0f * (a[8] / a[5] + a[9] / a[4]);
    const float svcl_b = 3.0f * (a[10] / a[7] + a[11] / a[6]);
    __shared__ float r[4][128];
    r[0][b] = vcl_b; r[1][b] = svcl_b; r[2][b] = icl_b; r[3][b] = sicl_b;
    __syncthreads();
    for (int s = 64; s > 0; s >>= 1) {
        if (b < s) {
            r[0][b] += r[0][b + s]; r[1][b] += r[1][b + s];
            r[2][b] += r[2][b + s]; r[3][b] += r[3][b + s];
        }
        __syncthreads();
    }
    if (b == 0) {
        out[0] = r[0][0] * (1.0f / 128.f);
        out[1] = r[1][0] * (1.0f / 128.f);
        out[2] = r[2][0] * (1.0f / 128.f);
        out[3] = r[3][0] * (1.0f / 128.f);
    }
}

__global__ void copy_mems(const float4* __restrict__ m0, const float4* __restrict__ m1,
                          float4* __restrict__ o0, float4* __restrict__ o1) {
    const int n4 = NMEM * D / 4;
    for (int i = blockIdx.x * blockDim.x + threadIdx.x; i < n4; i += gridDim.x * blockDim.x) {
        o0[i] = m0[i];
        o1[i] = m1[i];
    }
}

// One block per b; wave 0 -> net0, wave 1 -> net1. Last-write-wins on dup p0.
__global__ void update_rows(const float* __restrict__ emb0, const float* __restrict__ emb1,
                            const float* __restrict__ mem0, const float* __restrict__ mem1,
                            const int* __restrict__ pos_idx,
                            float* __restrict__ o0, float* __restrict__ o1) {
    const int b = blockIdx.x;
    const int tid = threadIdx.x;  // 128
    const int lane = tid & 63;
    const int net = tid >> 6;
    const int p0 = pos_idx[b * 2];
    bool skip = false;
    for (int b2 = b + 1; b2 < B; ++b2)
        if (pos_idx[b2 * 2] == p0) skip = true;  // numpy scatter: last write wins
    if (skip) return;  // uniform across block
    const float* mem = net ? mem1 : mem0;
    const float* emb = net ? emb1 : emb0;
    float* o = net ? o1 : o0;
    const float2 mv = *(const float2*)(mem + p0 * D + 2 * lane);
    const float2 ev = *(const float2*)(emb + b * D + 2 * lane);
    const float ux = 0.5f * mv.x + 0.5f * ev.x;
    const float uy = 0.5f * mv.y + 0.5f * ev.y;
    float ss = ux * ux + uy * uy;
    #pragma unroll
    for (int off = 1; off < 64; off <<= 1) ss += __shfl_xor(ss, off, 64);
    const float inv = 1.0f / sqrtf(ss);
    float2 wv; wv.x = ux * inv; wv.y = uy * inv;
    *(float2*)(o + p0 * D + 2 * lane) = wv;
}

extern "C" void kernel_launch(void* const* d_in, const int* in_sizes, int n_in,
                              void* d_out, int out_size, void* d_ws, size_t ws_size,
                              hipStream_t stream) {
    const float* emb0 = (const float*)d_in[0];
    const float* emb1 = (const float*)d_in[1];
    const float* mem0 = (const float*)d_in[2];
    const float* mem1 = (const float*)d_in[3];
    const int* pos_idx = (const int*)d_in[4];
    const int* neg_idx = (const int*)d_in[5];
    float* out = (float*)d_out;
    float* partials = (float*)d_ws;  // needs 128*16*20*4 = 160 KiB

    float* out_m0 = out + 4;
    float* out_m1 = out + 4 + NMEM * D;

    gather_logits<<<dim3(CHUNKS, B), 256, 0, stream>>>(emb0, emb1, mem0, mem1,
                                                       pos_idx, neg_idx, partials);
    finalize<<<1, 128, 0, stream>>>(partials, out);
    copy_mems<<<4096, 256, 0, stream>>>((const float4*)mem0, (const float4*)mem1,
                                        (float4*)out_m0, (float4*)out_m1);
    update_rows<<<B, 128, 0, stream>>>(emb0, emb1, mem0, mem1, pos_idx, out_m0, out_m1);
}